// Round 2
// baseline (173.953 us; speedup 1.0000x reference)
//
#include <hip/hip_runtime.h>

#define EPS_DEF 1.1920928955078125e-07f

// Geometry (fixed by reference setup_inputs):
//   x: (32,512,12,24)    -> 16384 slices of 288
//   y: (32,512,12,16)    -> 16384 slices of 192
//   z: (32,512,12,16,24) -> 16384 slices of 4608 (192 rows of 24)
//
// Block = 192 threads: thread t owns z-row t fully in registers (24 floats).
// x/y staged in LDS (tiny); rows 0..11 of x and y reduced+written by
// owner-threads 0..23. Only 2 barriers; z never touches LDS.

__launch_bounds__(192)
__global__ void fused_rms_kernel(const float* __restrict__ x,
                                 const float* __restrict__ y,
                                 const float* __restrict__ z,
                                 const float* __restrict__ w0,
                                 const float* __restrict__ w1,
                                 const float* __restrict__ w2,
                                 const float* __restrict__ w3,
                                 const float* __restrict__ w4,
                                 const float* __restrict__ w5,
                                 float* __restrict__ ox,
                                 float* __restrict__ oy,
                                 float* __restrict__ oz)
{
    __shared__ float xs[12 * 25];         // x slice, rows padded 24->25
    __shared__ float ys[12 * 17];         // y slice, rows padded 16->17
    __shared__ float w2sqs[24], w25s[24]; // w2^2, w2*w5
    __shared__ float w0sqs[24], w03s[24]; // w0^2, w0*w3
    __shared__ float w1sqs[192], w14s[192];
    __shared__ float wpart[3][4];         // per-wave partials (Sz, Sx, Sy0, Sy1)

    const int tid = threadIdx.x;
    const int bid = blockIdx.x;

    // ---- z row -> registers (per-lane 96B chunk; wave covers 6KB contiguous) ----
    const float4* zp4 = (const float4*)(z + (size_t)bid * 4608 + tid * 24);
    float zr[24];
    #pragma unroll
    for (int i = 0; i < 6; ++i) {
        float4 q = zp4[i];
        zr[4*i+0] = q.x; zr[4*i+1] = q.y; zr[4*i+2] = q.z; zr[4*i+3] = q.w;
    }

    // ---- stage x, y, weights into LDS ----
    if (tid < 72) {                        // x: 288/4 float4s
        float4 q = ((const float4*)(x + (size_t)bid * 288))[tid];
        int k = tid * 4, r = k / 24, c = k - r * 24;
        float* d = &xs[r * 25 + c];
        d[0] = q.x; d[1] = q.y; d[2] = q.z; d[3] = q.w;
    } else if (tid < 120) {                // y: 192/4 float4s
        int t = tid - 72;
        float4 q = ((const float4*)(y + (size_t)bid * 192))[t];
        int k = t * 4, r = k / 16, c = k - r * 16;
        float* d = &ys[r * 17 + c];
        d[0] = q.x; d[1] = q.y; d[2] = q.z; d[3] = q.w;
    } else if (tid < 144) {                // 24-wide weight combos
        int j = tid - 120;
        float a0 = w0[j], a2 = w2[j], a3 = w3[j], a5 = w5[j];
        w0sqs[j] = a0 * a0; w03s[j] = a0 * a3;
        w2sqs[j] = a2 * a2; w25s[j] = a2 * a5;
    }
    {                                       // w1-derived: one element per thread
        float a1 = w1[tid], a4 = w4[tid];
        w1sqs[tid] = a1 * a1;
        w14s[tid]  = a1 * a4;
    }
    __syncthreads();

    // ---- per-row reductions ----
    float s0 = 0.f, sw = 0.f;               // z row (registers, w2sq broadcast)
    #pragma unroll
    for (int j = 0; j < 24; ++j) {
        float v = zr[j];
        s0 = fmaf(v, v, s0);
        sw = fmaf(v * v, w2sqs[j], sw);
    }
    const float r1  = rsqrtf(s0 * (1.f / 24.f) + EPS_DEF);
    const float r1sq = r1 * r1;
    float p0 = r1sq * sw, p1 = 0.f, p2 = 0.f, p3 = 0.f;

    float r1x = 0.f, swx = 0.f, r1y = 0.f;  // per-owner-thread x/y state
    if (tid < 12) {
        const float* row = &xs[tid * 25];
        float a0 = 0.f, aw = 0.f;
        #pragma unroll
        for (int j = 0; j < 24; ++j) {
            float v = row[j];
            a0 = fmaf(v, v, a0);
            aw = fmaf(v * v, w0sqs[j], aw);
        }
        r1x = rsqrtf(a0 * (1.f / 24.f) + EPS_DEF);
        swx = aw;
        p1  = r1x * r1x * aw;
    } else if (tid < 24) {
        int i = tid - 12;
        const float* row = &ys[i * 17];
        const float* wq  = &w1sqs[i * 16];
        float a0 = 0.f, aw = 0.f;
        #pragma unroll
        for (int j = 0; j < 16; ++j) {
            float v = row[j];
            a0 = fmaf(v, v, a0);
            aw = fmaf(v * v, wq[j], aw);
        }
        r1y = rsqrtf(a0 * (1.f / 16.f) + 1e-3f);   // y step-1 eps
        p2  = r1y * r1y * a0;                       // unweighted, for step-2
        p3  = r1y * r1y * aw;                       // w1-weighted, for step-3
    }

    // ---- block reduction: wave shuffle + 3-wave LDS combine ----
    #pragma unroll
    for (int d = 32; d; d >>= 1) {
        p0 += __shfl_down(p0, d, 64);
        p1 += __shfl_down(p1, d, 64);
        p2 += __shfl_down(p2, d, 64);
        p3 += __shfl_down(p3, d, 64);
    }
    if ((tid & 63) == 0) {
        int w = tid >> 6;
        wpart[w][0] = p0; wpart[w][1] = p1; wpart[w][2] = p2; wpart[w][3] = p3;
    }
    __syncthreads();

    const float Sz  = wpart[0][0] + wpart[1][0] + wpart[2][0];
    const float Sx  = wpart[0][1] + wpart[1][1] + wpart[2][1];
    const float Sy0 = wpart[0][2] + wpart[1][2] + wpart[2][2];
    const float Sy1 = wpart[0][3] + wpart[1][3] + wpart[2][3];

    const float cZ  = rsqrtf(Sz  * (1.f / 4608.f) + 0.01f);   // z step-2 eps
    const float cX  = rsqrtf(Sx  * (1.f / 288.f)  + EPS_DEF);
    const float c2y = rsqrtf(Sy0 * (1.f / 192.f)  + EPS_DEF);
    const float c3y = rsqrtf(c2y * c2y * Sy1 * (1.f / 192.f) + EPS_DEF);

    // ---- z finalize + store (register-resident, no LDS) ----
    {
        float r3 = rsqrtf(cZ * cZ * r1sq * sw * (1.f / 24.f) + EPS_DEF);
        float az = r1 * cZ * r3;
        float4* op = (float4*)(oz + (size_t)bid * 4608 + tid * 24);
        #pragma unroll
        for (int i = 0; i < 6; ++i) {
            float4 q;
            q.x = zr[4*i+0] * az * w25s[4*i+0];
            q.y = zr[4*i+1] * az * w25s[4*i+1];
            q.z = zr[4*i+2] * az * w25s[4*i+2];
            q.w = zr[4*i+3] * az * w25s[4*i+3];
            op[i] = q;
        }
    }

    // ---- x/y finalize + store by owner threads (no extra barrier) ----
    if (tid < 12) {
        float r3 = rsqrtf(cX * cX * r1x * r1x * swx * (1.f / 24.f) + EPS_DEF);
        float ax = r1x * cX * r3;
        const float* row = &xs[tid * 25];
        float4* op = (float4*)(ox + (size_t)bid * 288 + tid * 24);
        #pragma unroll
        for (int i = 0; i < 6; ++i) {
            float4 q;
            q.x = row[4*i+0] * ax * w03s[4*i+0];
            q.y = row[4*i+1] * ax * w03s[4*i+1];
            q.z = row[4*i+2] * ax * w03s[4*i+2];
            q.w = row[4*i+3] * ax * w03s[4*i+3];
            op[i] = q;
        }
    } else if (tid < 24) {
        int i = tid - 12;
        float ay = r1y * c2y * c3y;
        const float* row = &ys[i * 17];
        const float* wf  = &w14s[i * 16];
        float4* op = (float4*)(oy + (size_t)bid * 192 + i * 16);
        #pragma unroll
        for (int k = 0; k < 4; ++k) {
            float4 q;
            q.x = row[4*k+0] * ay * wf[4*k+0];
            q.y = row[4*k+1] * ay * wf[4*k+1];
            q.z = row[4*k+2] * ay * wf[4*k+2];
            q.w = row[4*k+3] * ay * wf[4*k+3];
            op[k] = q;
        }
    }
}

extern "C" void kernel_launch(void* const* d_in, const int* in_sizes, int n_in,
                              void* d_out, int out_size, void* d_ws, size_t ws_size,
                              hipStream_t stream) {
    const float* x  = (const float*)d_in[0];
    const float* y  = (const float*)d_in[1];
    const float* z  = (const float*)d_in[2];
    const float* w0 = (const float*)d_in[3];
    const float* w1 = (const float*)d_in[4];
    const float* w2 = (const float*)d_in[5];
    const float* w3 = (const float*)d_in[6];
    const float* w4 = (const float*)d_in[7];
    const float* w5 = (const float*)d_in[8];

    float* out = (float*)d_out;
    const size_t NX = (size_t)32 * 512 * 12 * 24;   // 4718592
    const size_t NY = (size_t)32 * 512 * 12 * 16;   // 3145728
    float* ox = out;
    float* oy = out + NX;
    float* oz = out + NX + NY;

    const int nblk = 32 * 512;   // 16384
    hipLaunchKernelGGL(fused_rms_kernel, dim3(nblk), dim3(192), 0, stream,
                       x, y, z, w0, w1, w2, w3, w4, w5, ox, oy, oz);
}

// Round 3
// 130.592 us; speedup vs baseline: 1.3320x; 1.3320x over previous
//
#include <hip/hip_runtime.h>

#define EPS_DEF 1.1920928955078125e-07f

// Geometry (fixed by reference setup_inputs):
//   x: (32,512,12,24)    -> 16384 slices of 288
//   y: (32,512,12,16)    -> 16384 slices of 192
//   z: (32,512,12,16,24) -> 16384 slices of 4608 = 192 rows x 24
//
// Block = 192 threads (3 waves), one slice per block.
// z: thread t loads float4s v = t + 192*i (i=0..5) -- fully coalesced -- and
// keeps them in registers. Since 192 % 6 == 0, v % 6 == t % 6 (column group,
// thread-invariant) and v/6 = t/6 + 32*i (row, affine). Per-float4 partial
// sums (sum v^2, sum (v*w2)^2) go to LDS (8 B each); thread t then owns the
// full reduction of row t. Output written from the register copy.

__launch_bounds__(192)
__global__ void fused_rms_kernel(const float* __restrict__ x,
                                 const float* __restrict__ y,
                                 const float* __restrict__ z,
                                 const float* __restrict__ w0,
                                 const float* __restrict__ w1,
                                 const float* __restrict__ w2,
                                 const float* __restrict__ w3,
                                 const float* __restrict__ w4,
                                 const float* __restrict__ w5,
                                 float* __restrict__ ox,
                                 float* __restrict__ oy,
                                 float* __restrict__ oz)
{
    __shared__ __align__(16) float2 part[1152];  // z per-float4 partials (s0, sw)
    __shared__ float xs[12 * 25];                // x slice, rows padded 24->25
    __shared__ float ys[12 * 17];                // y slice, rows padded 16->17
    __shared__ float w0sqs[24], w03s[24];        // w0^2, w0*w3
    __shared__ float w1sqs[192], w14s[192];      // w1^2, w1*w4
    __shared__ float az[192];                    // z per-row combined scale
    __shared__ float wpart[3][4];                // per-wave block-sum partials

    const int tid = threadIdx.x;
    const int bid = blockIdx.x;
    const int j6  = tid % 6;        // column group (thread-invariant)
    const int c4  = j6 * 4;         // column offset of this thread's float4s
    const int r0  = tid / 6;        // base row; row(i) = r0 + 32*i

    // ---- per-thread column weights (4 regs each; L1-broadcast loads) ----
    float w2v[4], w5v[4];
    #pragma unroll
    for (int k = 0; k < 4; ++k) { w2v[k] = w2[c4 + k]; w5v[k] = w5[c4 + k]; }

    // ---- z -> registers, fully coalesced ----
    const float4* zp = (const float4*)(z + (size_t)bid * 4608);
    float4 zr[6];
    #pragma unroll
    for (int i = 0; i < 6; ++i) zr[i] = zp[tid + 192 * i];

    // ---- stage x, y, small weights into LDS ----
    if (tid < 72) {                           // x: 288/4 float4s
        float4 q = ((const float4*)(x + (size_t)bid * 288))[tid];
        int k = tid * 4, r = k / 24, c = k - r * 24;
        float* d = &xs[r * 25 + c];
        d[0] = q.x; d[1] = q.y; d[2] = q.z; d[3] = q.w;
    } else if (tid < 120) {                   // y: 192/4 float4s
        int t = tid - 72;
        float4 q = ((const float4*)(y + (size_t)bid * 192))[t];
        int k = t * 4, r = k / 16, c = k - r * 16;
        float* d = &ys[r * 17 + c];
        d[0] = q.x; d[1] = q.y; d[2] = q.z; d[3] = q.w;
    } else if (tid < 144) {                   // 24-wide x-weight combos
        int q = tid - 120;
        float a0 = w0[q], a3 = w3[q];
        w0sqs[q] = a0 * a0; w03s[q] = a0 * a3;
    }
    {                                          // y weights: one elem/thread
        float a1 = w1[tid], a4 = w4[tid];
        w1sqs[tid] = a1 * a1;
        w14s[tid]  = a1 * a4;
    }

    // ---- z per-float4 partials -> LDS (coalesced float2 writes) ----
    #pragma unroll
    for (int i = 0; i < 6; ++i) {
        float4 q = zr[i];
        float s0 = q.x * q.x;
        s0 = fmaf(q.y, q.y, s0); s0 = fmaf(q.z, q.z, s0); s0 = fmaf(q.w, q.w, s0);
        float t0 = q.x * w2v[0], t1 = q.y * w2v[1], t2 = q.z * w2v[2], t3 = q.w * w2v[3];
        float sw = t0 * t0;
        sw = fmaf(t1, t1, sw); sw = fmaf(t2, t2, sw); sw = fmaf(t3, t3, sw);
        part[tid + 192 * i] = make_float2(s0, sw);
    }
    __syncthreads();

    // ---- row reductions: thread t owns z-row t ----
    float s0 = 0.f, swz = 0.f;
    {
        const float4* pr = (const float4*)&part[6 * tid];  // 3x float4 = 6 float2
        #pragma unroll
        for (int k = 0; k < 3; ++k) {
            float4 p = pr[k];
            s0  += p.x + p.z;
            swz += p.y + p.w;
        }
    }
    const float r1   = rsqrtf(s0 * (1.f / 24.f) + EPS_DEF);
    const float r1sq = r1 * r1;
    float p0 = r1sq * swz, p1 = 0.f, p2 = 0.f, p3 = 0.f;

    float r1x = 0.f, swx = 0.f, r1y = 0.f;     // x/y owner-thread state
    if (tid < 12) {
        const float* row = &xs[tid * 25];
        float a0 = 0.f, aw = 0.f;
        #pragma unroll
        for (int j = 0; j < 24; ++j) {
            float v = row[j];
            a0 = fmaf(v, v, a0);
            aw = fmaf(v * v, w0sqs[j], aw);
        }
        r1x = rsqrtf(a0 * (1.f / 24.f) + EPS_DEF);
        swx = aw;
        p1  = r1x * r1x * aw;
    } else if (tid < 24) {
        int i = tid - 12;
        const float* row = &ys[i * 17];
        const float* wq  = &w1sqs[i * 16];
        float a0 = 0.f, aw = 0.f;
        #pragma unroll
        for (int j = 0; j < 16; ++j) {
            float v = row[j];
            a0 = fmaf(v, v, a0);
            aw = fmaf(v * v, wq[j], aw);
        }
        r1y = rsqrtf(a0 * (1.f / 16.f) + 1e-3f);  // y step-1 eps
        p2  = r1y * r1y * a0;                      // unweighted (step 2)
        p3  = r1y * r1y * aw;                      // w1-weighted (step 3)
    }

    // ---- block reduction: wave shuffle + 3-wave LDS combine ----
    #pragma unroll
    for (int d = 32; d; d >>= 1) {
        p0 += __shfl_down(p0, d, 64);
        p1 += __shfl_down(p1, d, 64);
        p2 += __shfl_down(p2, d, 64);
        p3 += __shfl_down(p3, d, 64);
    }
    if ((tid & 63) == 0) {
        int w = tid >> 6;
        wpart[w][0] = p0; wpart[w][1] = p1; wpart[w][2] = p2; wpart[w][3] = p3;
    }
    __syncthreads();

    const float Sz  = wpart[0][0] + wpart[1][0] + wpart[2][0];
    const float Sx  = wpart[0][1] + wpart[1][1] + wpart[2][1];
    const float Sy0 = wpart[0][2] + wpart[1][2] + wpart[2][2];
    const float Sy1 = wpart[0][3] + wpart[1][3] + wpart[2][3];

    const float cZ  = rsqrtf(Sz  * (1.f / 4608.f) + 0.01f);   // z step-2 eps
    const float cX  = rsqrtf(Sx  * (1.f / 288.f)  + EPS_DEF);
    const float c2y = rsqrtf(Sy0 * (1.f / 192.f)  + EPS_DEF);
    const float c3y = rsqrtf(c2y * c2y * Sy1 * (1.f / 192.f) + EPS_DEF);

    // ---- per-row combined z scale -> LDS broadcast ----
    {
        float r3 = rsqrtf(cZ * cZ * r1sq * swz * (1.f / 24.f) + EPS_DEF);
        az[tid] = r1 * cZ * r3;
    }
    __syncthreads();

    // ---- z output from registers (coalesced) ----
    {
        float w25r[4];
        #pragma unroll
        for (int k = 0; k < 4; ++k) w25r[k] = w2v[k] * w5v[k];
        float4* ozp = (float4*)(oz + (size_t)bid * 4608);
        #pragma unroll
        for (int i = 0; i < 6; ++i) {
            float a = az[r0 + 32 * i];
            float4 q = zr[i];
            q.x *= a * w25r[0];
            q.y *= a * w25r[1];
            q.z *= a * w25r[2];
            q.w *= a * w25r[3];
            ozp[tid + 192 * i] = q;
        }
    }

    // ---- x/y outputs by owner threads ----
    if (tid < 12) {
        float r3 = rsqrtf(cX * cX * r1x * r1x * swx * (1.f / 24.f) + EPS_DEF);
        float ax = r1x * cX * r3;
        const float* row = &xs[tid * 25];
        float4* op = (float4*)(ox + (size_t)bid * 288 + tid * 24);
        #pragma unroll
        for (int i = 0; i < 6; ++i) {
            float4 q;
            q.x = row[4*i+0] * ax * w03s[4*i+0];
            q.y = row[4*i+1] * ax * w03s[4*i+1];
            q.z = row[4*i+2] * ax * w03s[4*i+2];
            q.w = row[4*i+3] * ax * w03s[4*i+3];
            op[i] = q;
        }
    } else if (tid < 24) {
        int i = tid - 12;
        float ay = r1y * c2y * c3y;
        const float* row = &ys[i * 17];
        const float* wf  = &w14s[i * 16];
        float4* op = (float4*)(oy + (size_t)bid * 192 + i * 16);
        #pragma unroll
        for (int k = 0; k < 4; ++k) {
            float4 q;
            q.x = row[4*k+0] * ay * wf[4*k+0];
            q.y = row[4*k+1] * ay * wf[4*k+1];
            q.z = row[4*k+2] * ay * wf[4*k+2];
            q.w = row[4*k+3] * ay * wf[4*k+3];
            op[k] = q;
        }
    }
}

extern "C" void kernel_launch(void* const* d_in, const int* in_sizes, int n_in,
                              void* d_out, int out_size, void* d_ws, size_t ws_size,
                              hipStream_t stream) {
    const float* x  = (const float*)d_in[0];
    const float* y  = (const float*)d_in[1];
    const float* z  = (const float*)d_in[2];
    const float* w0 = (const float*)d_in[3];
    const float* w1 = (const float*)d_in[4];
    const float* w2 = (const float*)d_in[5];
    const float* w3 = (const float*)d_in[6];
    const float* w4 = (const float*)d_in[7];
    const float* w5 = (const float*)d_in[8];

    float* out = (float*)d_out;
    const size_t NX = (size_t)32 * 512 * 12 * 24;   // 4718592
    const size_t NY = (size_t)32 * 512 * 12 * 16;   // 3145728
    float* ox = out;
    float* oy = out + NX;
    float* oz = out + NX + NY;

    const int nblk = 32 * 512;   // 16384
    hipLaunchKernelGGL(fused_rms_kernel, dim3(nblk), dim3(192), 0, stream,
                       x, y, z, w0, w1, w2, w3, w4, w5, ox, oy, oz);
}

// Round 4
// 117.519 us; speedup vs baseline: 1.4802x; 1.1112x over previous
//
#include <hip/hip_runtime.h>

#define EPS_DEF 1.1920928955078125e-07f

typedef float f4 __attribute__((ext_vector_type(4)));

// Geometry (fixed by reference setup_inputs):
//   x: (32,512,12,24)    -> 16384 slices of 288
//   y: (32,512,12,16)    -> 16384 slices of 192
//   z: (32,512,12,16,24) -> 16384 slices of 4608 = 192 rows x 24
//
// Block = 192 threads (3 waves), one slice per block, 2 barriers.
// z: thread t loads float4s v = t + 192*i (i=0..5), fully coalesced, keeps
// them in registers. v%6 == t%6 (column group, thread-invariant weights) and
// v/6 = t/6 + 32*i (row, affine). Per-float4 partials -> LDS; thread t owns
// row t's reduction and publishes (r1, sw) to LDS; after the single
// block-sum barrier every storer recomputes its row scale (1 rsqrt).
// x/y staged flat in LDS; stores fully coalesced by 72/48 writer threads.
// All big streams use non-temporal loads/stores (single-use data).

__launch_bounds__(192)
__global__ void fused_rms_kernel(const float* __restrict__ x,
                                 const float* __restrict__ y,
                                 const float* __restrict__ z,
                                 const float* __restrict__ w0,
                                 const float* __restrict__ w1,
                                 const float* __restrict__ w2,
                                 const float* __restrict__ w3,
                                 const float* __restrict__ w4,
                                 const float* __restrict__ w5,
                                 float* __restrict__ ox,
                                 float* __restrict__ oy,
                                 float* __restrict__ oz)
{
    __shared__ __align__(16) float2 part[1152];   // z per-float4 partials (s0, sw)
    __shared__ __align__(16) float  xs[288];      // x slice, flat float4 mirror
    __shared__ __align__(16) float  ys[192];      // y slice, flat float4 mirror
    __shared__ float2 rw[192];                    // z per-row (r1, swz)
    __shared__ float2 rwx[12];                    // x per-row (r1x, swx)
    __shared__ float  rwy[12];                    // y per-row r1y
    __shared__ __align__(16) float w0sqs[24], w03s[24];   // w0^2, w0*w3
    __shared__ __align__(16) float w1sqs[192], w14s[192]; // w1^2, w1*w4
    __shared__ float wpart[3][4];                 // per-wave block-sum partials

    const int tid = threadIdx.x;
    const int bid = blockIdx.x;
    const int j6  = tid % 6;        // column group (thread-invariant)
    const int c4  = j6 * 4;         // column offset of this thread's float4s
    const int r0  = tid / 6;        // base row; row(i) = r0 + 32*i

    // ---- per-thread column weights (cached loads; reused by all blocks) ----
    float w2v[4], w5v[4];
    #pragma unroll
    for (int k = 0; k < 4; ++k) { w2v[k] = w2[c4 + k]; w5v[k] = w5[c4 + k]; }

    // ---- z -> registers, fully coalesced, non-temporal ----
    const f4* zp = (const f4*)(z + (size_t)bid * 4608);
    f4 zr[6];
    #pragma unroll
    for (int i = 0; i < 6; ++i)
        zr[i] = __builtin_nontemporal_load(zp + tid + 192 * i);

    // ---- stage x, y (flat), small weights into LDS ----
    if (tid < 72) {                           // x: 288/4 float4s
        f4 q = __builtin_nontemporal_load((const f4*)(x + (size_t)bid * 288) + tid);
        ((f4*)xs)[tid] = q;
    } else if (tid < 120) {                   // y: 192/4 float4s
        int t = tid - 72;
        f4 q = __builtin_nontemporal_load((const f4*)(y + (size_t)bid * 192) + t);
        ((f4*)ys)[t] = q;
    } else if (tid < 144) {                   // 24-wide x-weight combos
        int q = tid - 120;
        float a0 = w0[q], a3 = w3[q];
        w0sqs[q] = a0 * a0; w03s[q] = a0 * a3;
    }
    {                                          // y weights: one elem/thread
        float a1 = w1[tid], a4 = w4[tid];
        w1sqs[tid] = a1 * a1;
        w14s[tid]  = a1 * a4;
    }

    // ---- z per-float4 partials -> LDS ----
    #pragma unroll
    for (int i = 0; i < 6; ++i) {
        f4 q = zr[i];
        float s0 = q.x * q.x;
        s0 = fmaf(q.y, q.y, s0); s0 = fmaf(q.z, q.z, s0); s0 = fmaf(q.w, q.w, s0);
        float t0 = q.x * w2v[0], t1 = q.y * w2v[1], t2 = q.z * w2v[2], t3 = q.w * w2v[3];
        float sw = t0 * t0;
        sw = fmaf(t1, t1, sw); sw = fmaf(t2, t2, sw); sw = fmaf(t3, t3, sw);
        part[tid + 192 * i] = make_float2(s0, sw);
    }
    __syncthreads();   // barrier 1: partials + staged x/y visible

    // ---- row reductions: thread t owns z-row t; publish (r1, swz) ----
    float s0 = 0.f, swz = 0.f;
    {
        const f4* pr = (const f4*)&part[6 * tid];  // 3x float4 = 6 float2
        #pragma unroll
        for (int k = 0; k < 3; ++k) {
            f4 p = pr[k];
            s0  += p.x + p.z;
            swz += p.y + p.w;
        }
    }
    const float r1 = rsqrtf(s0 * (1.f / 24.f) + EPS_DEF);
    rw[tid] = make_float2(r1, swz);
    float p0 = r1 * r1 * swz, p1 = 0.f, p2 = 0.f, p3 = 0.f;

    if (tid < 12) {                            // x row owners
        const float* row = &xs[tid * 24];
        float a0 = 0.f, aw = 0.f;
        #pragma unroll
        for (int j = 0; j < 24; ++j) {
            float v = row[j];
            a0 = fmaf(v, v, a0);
            aw = fmaf(v * v, w0sqs[j], aw);
        }
        float r1x = rsqrtf(a0 * (1.f / 24.f) + EPS_DEF);
        rwx[tid] = make_float2(r1x, aw);
        p1 = r1x * r1x * aw;
    } else if (tid < 24) {                     // y row owners
        int i = tid - 12;
        const float* row = &ys[i * 16];
        const float* wq  = &w1sqs[i * 16];
        float a0 = 0.f, aw = 0.f;
        #pragma unroll
        for (int j = 0; j < 16; ++j) {
            float v = row[j];
            a0 = fmaf(v, v, a0);
            aw = fmaf(v * v, wq[j], aw);
        }
        float r1y = rsqrtf(a0 * (1.f / 16.f) + 1e-3f);  // y step-1 eps
        rwy[i] = r1y;
        p2 = r1y * r1y * a0;                   // unweighted (step 2)
        p3 = r1y * r1y * aw;                   // w1-weighted (step 3)
    }

    // ---- block reduction: wave shuffle + 3-wave LDS combine ----
    #pragma unroll
    for (int d = 32; d; d >>= 1) {
        p0 += __shfl_down(p0, d, 64);
        p1 += __shfl_down(p1, d, 64);
        p2 += __shfl_down(p2, d, 64);
        p3 += __shfl_down(p3, d, 64);
    }
    if ((tid & 63) == 0) {
        int w = tid >> 6;
        wpart[w][0] = p0; wpart[w][1] = p1; wpart[w][2] = p2; wpart[w][3] = p3;
    }
    __syncthreads();   // barrier 2: block sums + per-row state visible

    const float Sz  = wpart[0][0] + wpart[1][0] + wpart[2][0];
    const float Sx  = wpart[0][1] + wpart[1][1] + wpart[2][1];
    const float Sy0 = wpart[0][2] + wpart[1][2] + wpart[2][2];
    const float Sy1 = wpart[0][3] + wpart[1][3] + wpart[2][3];

    const float cZ  = rsqrtf(Sz  * (1.f / 4608.f) + 0.01f);   // z step-2 eps
    const float cX  = rsqrtf(Sx  * (1.f / 288.f)  + EPS_DEF);
    const float c2y = rsqrtf(Sy0 * (1.f / 192.f)  + EPS_DEF);
    const float c3y = rsqrtf(c2y * c2y * Sy1 * (1.f / 192.f) + EPS_DEF);
    const float cZsq = cZ * cZ;

    // ---- z store from registers (coalesced, NT); recompute r3 per row ----
    {
        float w25r[4];
        #pragma unroll
        for (int k = 0; k < 4; ++k) w25r[k] = w2v[k] * w5v[k];
        f4* ozp = (f4*)(oz + (size_t)bid * 4608);
        #pragma unroll
        for (int i = 0; i < 6; ++i) {
            float2 rr = rw[r0 + 32 * i];
            float r3 = rsqrtf(cZsq * rr.x * rr.x * rr.y * (1.f / 24.f) + EPS_DEF);
            float a  = rr.x * cZ * r3;
            f4 q = zr[i];
            q.x *= a * w25r[0];
            q.y *= a * w25r[1];
            q.z *= a * w25r[2];
            q.w *= a * w25r[3];
            __builtin_nontemporal_store(q, ozp + tid + 192 * i);
        }
    }

    // ---- x / y stores: fully coalesced writer threads ----
    if (tid < 72) {                            // x: one float4 per thread
        int row = tid / 6;
        float2 rr = rwx[row];
        float r3 = rsqrtf(cX * cX * rr.x * rr.x * rr.y * (1.f / 24.f) + EPS_DEF);
        float ax = rr.x * cX * r3;
        f4 q = ((const f4*)xs)[tid];
        f4 wf = ((const f4*)w03s)[tid % 6];
        q.x *= ax * wf.x;
        q.y *= ax * wf.y;
        q.z *= ax * wf.z;
        q.w *= ax * wf.w;
        __builtin_nontemporal_store(q, (f4*)(ox + (size_t)bid * 288) + tid);
    } else if (tid < 120) {                    // y: one float4 per thread
        int t = tid - 72;
        float ay = rwy[t / 4] * c2y * c3y;
        f4 q = ((const f4*)ys)[t];
        f4 wf = ((const f4*)w14s)[t];
        q.x *= ay * wf.x;
        q.y *= ay * wf.y;
        q.z *= ay * wf.z;
        q.w *= ay * wf.w;
        __builtin_nontemporal_store(q, (f4*)(oy + (size_t)bid * 192) + t);
    }
}

extern "C" void kernel_launch(void* const* d_in, const int* in_sizes, int n_in,
                              void* d_out, int out_size, void* d_ws, size_t ws_size,
                              hipStream_t stream) {
    const float* x  = (const float*)d_in[0];
    const float* y  = (const float*)d_in[1];
    const float* z  = (const float*)d_in[2];
    const float* w0 = (const float*)d_in[3];
    const float* w1 = (const float*)d_in[4];
    const float* w2 = (const float*)d_in[5];
    const float* w3 = (const float*)d_in[6];
    const float* w4 = (const float*)d_in[7];
    const float* w5 = (const float*)d_in[8];

    float* out = (float*)d_out;
    const size_t NX = (size_t)32 * 512 * 12 * 24;   // 4718592
    const size_t NY = (size_t)32 * 512 * 12 * 16;   // 3145728
    float* ox = out;
    float* oy = out + NX;
    float* oz = out + NX + NY;

    const int nblk = 32 * 512;   // 16384
    hipLaunchKernelGGL(fused_rms_kernel, dim3(nblk), dim3(192), 0, stream,
                       x, y, z, w0, w1, w2, w3, w4, w5, ox, oy, oz);
}